// Round 10
// baseline (301.516 us; speedup 1.0000x reference)
//
#include <hip/hip_runtime.h>
#include <math.h>

#define HW_   40000      // H*W = 200*200
#define NQ_   40000
#define IMGW  200
#define IMGH  200

typedef __bf16 bf16;
typedef __attribute__((ext_vector_type(4))) __bf16 bf16x4;
typedef __attribute__((ext_vector_type(8))) __bf16 bf16x8;
typedef __attribute__((ext_vector_type(4))) float f32x4;

__device__ __forceinline__ void gload_lds16(const void* g, void* l) {
  __builtin_amdgcn_global_load_lds(
      (const __attribute__((address_space(1))) void*)g,
      (__attribute__((address_space(3))) void*)l, 16, 0, 0);
}

// ---------------------------------------------------------------------------
// Prep: weight cast+transpose only. 896 blocks x 256 = 229376 elements.
// ---------------------------------------------------------------------------
__global__ __launch_bounds__(256) void prep_kernel(
    const float* __restrict__ Wv, const float* __restrict__ Wso,
    const float* __restrict__ Waw, const float* __restrict__ Wo,
    bf16* __restrict__ BtV, bf16* __restrict__ BtOA, bf16* __restrict__ BtO)
{
  int idx = blockIdx.x * 256 + threadIdx.x;
  if (idx < 65536) {
    int k = idx >> 8, n = idx & 255;
    BtV[(size_t)n * 256 + k] = (bf16)Wv[idx];
  } else if (idx < 131072) {
    int j = idx - 65536;
    int k = j >> 7, n = j & 127;
    BtOA[(size_t)n * 512 + k] = (bf16)Wso[j];
  } else if (idx < 163840) {
    int j = idx - 131072;
    int k = j >> 6, n = j & 63;
    BtOA[(size_t)(128 + n) * 512 + k] = (bf16)Waw[j];
  } else if (idx < 229376) {
    int j = idx - 163840;
    int k = j >> 8, n = j & 255;
    BtO[(size_t)n * 256 + k] = (bf16)Wo[j];
  }
}

// ---------------------------------------------------------------------------
// MFMA bf16 GEMM, 64 x BN block, N-split (R9 structure; 0 bank conflicts).
// Byte-model round: every bulk kernel here sits at ~3-3.5 TB/s effective
// fabric BW, so this round cuts BYTES, not schedule.
// ASRC 0: A bf16 rows via global_load_lds (out-GEMM: single ms).
// ASRC 1: A fp32 rows (single A0, KT=256), reg-convert + swizzled ds_write.
//         EMIT=1: y==0 blocks also store the converted bf16 row chunk to
//         val_bf (rows < 40000) -> offaw reads bf16 instead of fp32.
// ASRC 3: mixed K: kt<256 -> bf16 gload_lds from A0 (val_bf);
//         kt>=256 -> fp32 reg-convert from A1 (query).
// MODE 0: vproj -> bf16 (nbq,h,pix,hd), +bias0
// MODE 1: offaw -> off_g (16,40000,8) +bias0 / aw_g (16,40000,4) +bias1
// MODE 2: out   -> fp32 +bias0 +resid
// ---------------------------------------------------------------------------
template<int KT, int MODE, int BN, int ASRC, int EMIT>
__global__ __launch_bounds__(256) void mfma_gemm_kernel(
    const void* __restrict__ A0, const void* __restrict__ A1,
    const bf16* __restrict__ Bt,
    const float* __restrict__ bias0, const float* __restrict__ bias1,
    const float* __restrict__ resid,
    void* __restrict__ outp, void* __restrict__ outp2, int M)
{
  constexpr int NT16 = BN / 32;        // n-frags per wave (4 or 3)
  constexpr int NCH  = BN * 4;         // B 16-B chunks per tile
  constexpr int BCHN = (NCH + 255) / 256;
  constexpr int NIT  = KT / 32;        // K-steps (8 or 16)
  __shared__ bf16 As[2][64 * 32];      // 2 x 4 KB
  __shared__ bf16 Bs[2][BN * 32];      // 2 x 8/6 KB
  const int t    = threadIdx.x;
  const int m0   = blockIdx.x * 64;
  const int n0   = blockIdx.y * BN;
  const int w    = t >> 6;
  const int lane = t & 63;
  const int quad = lane >> 4;
  const int l16  = lane & 15;
  const int wm   = (w & 1) * 32;
  const int wn   = (w >> 1) * (BN / 2);

  f32x4 acc[2][NT16] = {};

  int gmA;
  {
    int gm = m0 + (t >> 2);
    gmA = (gm >= M) ? (M - 1) : gm;
  }
  const int arow = t >> 2;
  const int akey = (arow >> 1) & 3;

  float4 apf[2];      // fp32 staging regs

  auto issueB = [&](int it) {
    const int kt  = it * 32;
    const int buf = it & 1;
#pragma unroll
    for (int i = 0; i < BCHN; ++i) {
      int c = i * 256 + t;
      if (NCH % 256 != 0 && c >= NCH) break;
      int row = c >> 2;
      int j   = (c & 3) ^ ((row >> 1) & 3);     // source-chunk permutation
      gload_lds16(&Bt[(size_t)(n0 + row) * KT + kt + j * 8], &Bs[buf][c * 8]);
    }
  };

  auto issueA_lds = [&](int it, const bf16* Ap) {  // bf16 source
    const int kt  = it * 32;
    int j = (t & 3) ^ akey;
    gload_lds16(&Ap[(size_t)gmA * 256 + kt + j * 8], &As[it & 1][t * 8]);
  };

  auto loadA_reg = [&](int it) {                   // fp32 source -> regs
    const int kt = it * 32;
    const float* Ap = (ASRC == 3) ? (const float*)A1 : (const float*)A0;
    const int col = kt & 255;                      // kt or kt-256
    const float4* s4 = (const float4*)&Ap[(size_t)gmA * 256 + col + (t & 3) * 8];
    apf[0] = s4[0];
    apf[1] = s4[1];
  };

  auto writeA = [&](int it) {                      // convert + swizzled ds_write
    const int kt  = it * 32;
    const int buf = it & 1;
    int j = (t & 3) ^ akey;
    bf16x8 o = {(bf16)apf[0].x, (bf16)apf[0].y, (bf16)apf[0].z, (bf16)apf[0].w,
                (bf16)apf[1].x, (bf16)apf[1].y, (bf16)apf[1].z, (bf16)apf[1].w};
    *(bf16x8*)&As[buf][arow * 32 + j * 8] = o;
    if (EMIT) {                                    // bf16 copy for offaw
      if (blockIdx.y == 0 && gmA < 40000)
        *(bf16x8*)&((bf16*)outp2)[(size_t)gmA * 256 + kt + (t & 3) * 8] = o;
    }
  };

  auto stageA_issue = [&](int it) {
    if (ASRC == 0)      issueA_lds(it, (const bf16*)A0);
    else if (ASRC == 1) loadA_reg(it);
    else {              // ASRC 3: mixed
      if (it * 32 < 256) issueA_lds(it, (const bf16*)A0);
      else               loadA_reg(it);
    }
  };
  auto stageA_write = [&](int it) {
    if (ASRC == 1)                         writeA(it);
    else if (ASRC == 3 && it * 32 >= 256)  writeA(it);
  };

  stageA_issue(0); issueB(0); stageA_write(0);

#pragma unroll
  for (int it = 0; it < NIT; ++it) {
    __syncthreads();                       // drains tile-it loads/writes
    if (it + 1 < NIT) {                    // overlaps the MFMA block below
      issueB(it + 1);
      stageA_issue(it + 1);
    }
    const bf16* as = As[it & 1];
    const bf16* bs = Bs[it & 1];
    bf16x8 af[2], bfr[NT16];
#pragma unroll
    for (int x = 0; x < 2; ++x) {
      int row = wm + x * 16 + l16;
      af[x] = *(const bf16x8*)&as[row * 32 + (quad ^ ((row >> 1) & 3)) * 8];
    }
#pragma unroll
    for (int x = 0; x < NT16; ++x) {
      int row = wn + x * 16 + l16;
      bfr[x] = *(const bf16x8*)&bs[row * 32 + (quad ^ ((row >> 1) & 3)) * 8];
    }
#pragma unroll
    for (int mt = 0; mt < 2; ++mt)
#pragma unroll
      for (int nt = 0; nt < NT16; ++nt)
        acc[mt][nt] = __builtin_amdgcn_mfma_f32_16x16x32_bf16(
            af[mt], bfr[nt], acc[mt][nt], 0, 0, 0);
    if (it + 1 < NIT) stageA_write(it + 1);   // to the free buffer
  }

  // ---- epilogue (D: col = lane&15, row = quad*4 + reg) ----
#pragma unroll
  for (int mt = 0; mt < 2; ++mt) {
#pragma unroll
    for (int r = 0; r < 4; ++r) {
      const int gm = m0 + wm + mt * 16 + quad * 4 + r;
      if (gm >= M) continue;
#pragma unroll
      for (int nt = 0; nt < NT16; ++nt) {
        const int gn = n0 + wn + nt * 16 + l16;
        float v = acc[mt][nt][r];
        if (MODE == 0) {
          int nbq = (gm >= HW_) ? 1 : 0;
          int pix = gm - nbq * HW_;
          int h = gn >> 5, hd = gn & 31;
          ((bf16*)outp)[(((size_t)(nbq * 8 + h) * HW_ + pix) << 5) + hd] =
              (bf16)(v + bias0[gn]);
        } else if (MODE == 1) {
          if (gn < 128) {
            int gg = gn >> 3, e = gn & 7;    // g-major: off_g[g][q][8]
            ((bf16*)outp)[((size_t)gg * NQ_ + gm) * 8 + e] = (bf16)(v + bias0[gn]);
          } else {
            int j = gn - 128;
            int gg = j >> 2, e = j & 3;      // g-major: aw_g[g][q][4]
            ((bf16*)outp2)[((size_t)gg * NQ_ + gm) * 4 + e] = (bf16)(v + bias1[j]);
          }
        } else {
          ((float*)outp)[(size_t)gm * 256 + gn] =
              v + bias0[gn] + resid[(size_t)gm * 256 + gn];
        }
      }
    }
  }
}

// ---------------------------------------------------------------------------
// Deform sampling v4: R5-verified lane map (in-wave nbq merge -> SINGLE ms,
// halves deform writes and out-GEMM reads) + R6's full-ILP 16-load body +
// g-major off/aw. h = blockIdx&7 pins both nbq planes of a head to one XCD
// (5.1 MB working set). lane = qi*8 + nbq*4 + sub; shfl_xor(4) pairs nbq.
// ---------------------------------------------------------------------------
__global__ __launch_bounds__(256) void deform_attn_kernel(
    const bf16* __restrict__ vws,     // (2,8,40000,32) bf16
    const bf16* __restrict__ off_g,   // (16,40000,8) bf16
    const bf16* __restrict__ aw_g,    // (16,40000,4) bf16
    const float* __restrict__ ref,    // (40000,2)
    bf16* __restrict__ ms)            // (40000,256) bf16
{
  const int t    = threadIdx.x;
  const int w    = t >> 6;
  const int lane = t & 63;
  const int h    = blockIdx.x & 7;        // head pinned to XCD
  const int qb   = blockIdx.x >> 3;       // 0..1249
  const int qi   = lane >> 3;             // 0..7
  const int nbq  = (lane >> 2) & 1;
  const int sub  = lane & 3;
  const int q    = qb * 32 + w * 8 + qi;
  const int g    = h * 2 + nbq;

  const float rx = ref[2 * q + 0] * (float)IMGW - 0.5f;
  const float ry = ref[2 * q + 1] * (float)IMGH - 0.5f;

  bf16x4 a4 = *(const bf16x4*)&aw_g[((size_t)g * NQ_ + q) * 4];
  float aa0 = (float)a4[0], aa1 = (float)a4[1], aa2 = (float)a4[2], aa3 = (float)a4[3];
  float mx = fmaxf(fmaxf(aa0, aa1), fmaxf(aa2, aa3));
  float e0 = __expf(aa0 - mx), e1 = __expf(aa1 - mx);
  float e2 = __expf(aa2 - mx), e3 = __expf(aa3 - mx);
  float inv = 1.0f / (e0 + e1 + e2 + e3);
  float w4[4] = {e0 * inv, e1 * inv, e2 * inv, e3 * inv};

  bf16x8 o8 = *(const bf16x8*)&off_g[((size_t)g * NQ_ + q) * 8];

  const bf16* vbase = vws + (((size_t)(nbq * 8 + h) * HW_) << 5) + sub * 8;

  // ---- compute all 16 (weight, addr) and issue all 16 loads up front ----
  float  ww[16];
  bf16x8 v[16];
#pragma unroll
  for (int p = 0; p < 4; ++p) {
    float x = rx + (float)o8[2 * p];
    float y = ry + (float)o8[2 * p + 1];
    float xf = floorf(x), yf = floorf(y);
    int   x0 = (int)xf,   y0 = (int)yf;
    float lx = x - xf,    ly = y - yf;
    int   x1 = x0 + 1,    y1 = y0 + 1;
    float w00 = (1.0f - lx) * (1.0f - ly);
    float w01 = lx * (1.0f - ly);
    float w10 = (1.0f - lx) * ly;
    float w11 = lx * ly;
    if (x0 < 0 || x0 >= IMGW) { w00 = 0.0f; w10 = 0.0f; }
    if (x1 < 0 || x1 >= IMGW) { w01 = 0.0f; w11 = 0.0f; }
    if (y0 < 0 || y0 >= IMGH) { w00 = 0.0f; w01 = 0.0f; }
    if (y1 < 0 || y1 >= IMGH) { w10 = 0.0f; w11 = 0.0f; }
    int xc0 = min(max(x0, 0), IMGW - 1), xc1 = min(max(x1, 0), IMGW - 1);
    int yc0 = min(max(y0, 0), IMGH - 1), yc1 = min(max(y1, 0), IMGH - 1);
    float wp = w4[p];
    ww[4 * p + 0] = wp * w00;
    ww[4 * p + 1] = wp * w01;
    ww[4 * p + 2] = wp * w10;
    ww[4 * p + 3] = wp * w11;
    v[4 * p + 0] = *(const bf16x8*)&vbase[(size_t)(yc0 * IMGW + xc0) << 5];
    v[4 * p + 1] = *(const bf16x8*)&vbase[(size_t)(yc0 * IMGW + xc1) << 5];
    v[4 * p + 2] = *(const bf16x8*)&vbase[(size_t)(yc1 * IMGW + xc0) << 5];
    v[4 * p + 3] = *(const bf16x8*)&vbase[(size_t)(yc1 * IMGW + xc1) << 5];
  }

  float acc[8] = {};
#pragma unroll
  for (int s = 0; s < 16; ++s)
#pragma unroll
    for (int j = 0; j < 8; ++j)
      acc[j] = fmaf(ww[s], (float)v[s][j], acc[j]);

#pragma unroll
  for (int j = 0; j < 8; ++j) acc[j] += __shfl_xor(acc[j], 4);

  if (nbq == 0) {
    bf16x8 o;
#pragma unroll
    for (int j = 0; j < 8; ++j) o[j] = (bf16)(0.5f * acc[j]);
    *(bf16x8*)&ms[(size_t)q * 256 + h * 32 + sub * 8] = o;
  }
}

extern "C" void kernel_launch(void* const* d_in, const int* in_sizes, int n_in,
                              void* d_out, int out_size, void* d_ws, size_t ws_size,
                              hipStream_t stream) {
  const float* query = (const float*)d_in[0];   // (1, 40000, 256)
  const float* value = (const float*)d_in[1];   // (1, 80000, 256)
  const float* ref   = (const float*)d_in[2];   // (1, 40000, 1, 2)
  const float* Wv  = (const float*)d_in[4];
  const float* bv  = (const float*)d_in[5];
  const float* Wso = (const float*)d_in[6];
  const float* bso = (const float*)d_in[7];
  const float* Waw = (const float*)d_in[8];
  const float* baw = (const float*)d_in[9];
  const float* Wo  = (const float*)d_in[10];
  const float* bo  = (const float*)d_in[11];
  float* out = (float*)d_out;

  char* p = (char*)d_ws;
  bf16* vws    = (bf16*)p; p += (size_t)2 * 8 * HW_ * 32 * 2;   // 40.96 MB
  bf16* off_g  = (bf16*)p; p += (size_t)16 * NQ_ * 8 * 2;       // 10.24 MB
  bf16* aw_g   = (bf16*)p; p += (size_t)16 * NQ_ * 4 * 2;       //  5.12 MB
  bf16* ms     = (bf16*)p; p += (size_t)NQ_ * 256 * 2;          // 20.48 MB
  bf16* val_bf = (bf16*)p; p += (size_t)NQ_ * 256 * 2;          // 20.48 MB
  bf16* BtV    = (bf16*)p; p += (size_t)256 * 256 * 2;
  bf16* BtOA   = (bf16*)p; p += (size_t)192 * 512 * 2;
  bf16* BtO    = (bf16*)p; p += (size_t)256 * 256 * 2;

  // weights only
  prep_kernel<<<896, 256, 0, stream>>>(Wv, Wso, Waw, Wo, BtV, BtOA, BtO);

  // vproj: value fp32 (80000x256) @ (256x256) -> vws; also emits val_bf
  // (bf16 copy of rows <40000, y==0 blocks) for offaw.
  mfma_gemm_kernel<256, 0, 128, 1, 1><<<dim3(1250, 2), 256, 0, stream>>>(
      value, nullptr, BtV, bv, nullptr, nullptr, vws, val_bf, 2 * HW_);
  // offaw: qe = [val_bf (bf16) | query (fp32)] (40000x512) @ (512x192)
  mfma_gemm_kernel<512, 1, 96, 3, 0><<<dim3(625, 2), 256, 0, stream>>>(
      val_bf, query, BtOA, bso, baw, nullptr, off_g, aw_g, NQ_);
  // sampling (in-wave nbq merge -> single ms; XCD-partitioned by head)
  deform_attn_kernel<<<10000, 256, 0, stream>>>(vws, off_g, aw_g, ref, ms);
  // out: ms bf16 (40000x256) @ (256x256) + b + residual
  mfma_gemm_kernel<256, 2, 128, 0, 0><<<dim3(625, 2), 256, 0, stream>>>(
      ms, nullptr, BtO, bo, nullptr, query, out, nullptr, NQ_);
}